// Round 6
// baseline (68.787 us; speedup 1.0000x reference)
//
#include <hip/hip_runtime.h>

namespace {

constexpr int TPB = 256;   // 4 waves; each wave computes one part of all 64 elements
constexpr int EPB = 64;    // elements per tile
constexpr int TILES = 4;   // tiles per block (grid-stride persistent blocks)

typedef float f32x4 __attribute__((ext_vector_type(4)));  // native vector: OK for nontemporal builtins

__device__ __forceinline__ float clampf(float x, float lo, float hi) {
  return fminf(fmaxf(x, lo), hi);
}

// Wave-specialized FK (constants folded): wave 0 = root + finger A,
// wave 1 = fingers B + C, wave 2 = little finger, wave 3 = thumb.
// R5/R6: persistent blocks (2048 x 4 tiles) + nontemporal loads/stores to cut
// dispatch count 4x and bypass L2 write-allocate on the 132 MB store stream.

__global__ __launch_bounds__(TPB, 8) void fk_kernel(
    const float* __restrict__ angles,
    float* __restrict__ out) {
  // 16128 B: per tile, angles staged in first 5888 B (64 x 23 f32), then the
  // whole buffer becomes 64 rows x 63 f32 of output staging.
  __shared__ float lds[EPB * 63];

  const int tid = threadIdx.x;
  const int lane = tid & 63;
  const int w = tid >> 6;  // wave id 0..3 (wave-uniform)

#pragma unroll 1
  for (int t = 0; t < TILES; ++t) {
    const long long base = ((long long)blockIdx.x * TILES + t) * EPB;

    if (t > 0) __syncthreads();  // prior tile's store-phase LDS reads done

    // ---- coalesced stage of this tile's angles (368 x f32x4, 256 threads) ----
    {
      const f32x4* __restrict__ src = reinterpret_cast<const f32x4*>(angles + base * 23);
      f32x4* dst = reinterpret_cast<f32x4*>(lds);
      dst[tid] = __builtin_nontemporal_load(src + tid);
      if (tid + TPB < (EPB * 23) / 4)
        dst[tid + TPB] = __builtin_nontemporal_load(src + tid + TPB);
    }
    __syncthreads();

    const float* al = lds + lane * 23;  // this wave's element = lane
    float o[24];                        // literal-indexed only

    const float a0 = clampf(al[0], -0.689f, 0.489f);
    const float s0 = __sinf(a0);
    const float c0 = __cosf(a0);

// ---- finger macro: t=(TX,0,TZ), Ry(knuckle al[J]), then 3x Rx with
// z-links 0.045/0.025/0.026. Writes o[OB..OB+11] (4 rows). ----
#define FINGER(TX, TZ, J, OB)                                                   \
  {                                                                             \
    const float aY = clampf(al[(J)], -0.349f, 0.349f);                          \
    const float sY = __sinf(aY), cY = __cosf(aY);                               \
    const float g1 = clampf(al[(J) + 1], 0.0f, 1.571f);                         \
    const float g2 = g1 + clampf(al[(J) + 2], 0.0f, 1.571f);                    \
    const float g3 = g2 + clampf(al[(J) + 3], 0.0f, 1.571f);                    \
    const float s1 = __sinf(g1), c1 = __cosf(g1);                               \
    const float s2 = __sinf(g2), c2 = __cosf(g2);                               \
    const float s3 = __sinf(g3), c3 = __cosf(g3);                               \
    const float t1x = (TX), t1y = -s0 * (TZ), t1z = c0 * (TZ);                  \
    const float vx = sY, vy = -s0 * cY, vz = c0 * cY; /* frame col2 */          \
    /* frame col1 = (0, c0, s0) */                                              \
    const float q3y = -0.045f * s1, q3z = 0.045f * c1;                          \
    const float q4y = q3y - 0.025f * s2, q4z = q3z + 0.025f * c2;               \
    const float q5y = q4y - 0.026f * s3, q5z = q4z + 0.026f * c3;               \
    o[(OB) + 0] = t1x; o[(OB) + 1] = t1y; o[(OB) + 2] = t1z;                    \
    o[(OB) + 3] = t1x + q3z * vx;                                               \
    o[(OB) + 4] = t1y + q3y * c0 + q3z * vy;                                    \
    o[(OB) + 5] = t1z + q3y * s0 + q3z * vz;                                    \
    o[(OB) + 6] = t1x + q4z * vx;                                               \
    o[(OB) + 7] = t1y + q4y * c0 + q4z * vy;                                    \
    o[(OB) + 8] = t1z + q4y * s0 + q4z * vz;                                    \
    o[(OB) + 9] = t1x + q5z * vx;                                               \
    o[(OB) + 10] = t1y + q5y * c0 + q5z * vy;                                   \
    o[(OB) + 11] = t1z + q5y * s0 + q5z * vz;                                   \
  }

    if (w == 0) {
      // root (row 0) + finger A (rows 5-8)
      o[0] = 0.0f; o[1] = 0.0f; o[2] = 0.0f;
      FINGER(0.033f, 0.095f, 1, 3)
    } else if (w == 1) {
      // finger B (rows 9-12) + finger C (rows 13-16)
      FINGER(0.011f, 0.099f, 5, 0)
      FINGER(-0.011f, 0.095f, 9, 12)
    } else if (w == 2) {
      // little finger w/ metacarpal: Rodrigues about w=(0.571,0,0.821),
      // then Ry, then 3x Rx. Rows 17-20 -> o[0..11].
      const float a13 = clampf(al[13], 0.0f, 0.785f);
      const float wx = 0.571f, wz = 0.821f;
      const float s13 = __sinf(a13), c13 = __cosf(a13);
      const float t13 = 1.0f - c13;
      const float g00 = 1.0f - t13 * (wz * wz), g10 = s13 * wz, g20 = t13 * (wx * wz);
      const float g01 = -s13 * wz, g11 = 1.0f - t13 * (wx * wx + wz * wz), g21 = s13 * wx;
      const float g02 = t13 * (wx * wz), g12 = -s13 * wx, g22 = 1.0f - t13 * (wx * wx);
      const float gdx = -0.017f * g00 + 0.044f * g02;
      const float gdy = -0.017f * g10 + 0.044f * g12;
      const float gdz = -0.017f * g20 + 0.044f * g22;
      const float t17x = -0.017f + gdx;
      const float t17y = -0.044f * s0 + (c0 * gdy - s0 * gdz);
      const float t17z = 0.044f * c0 + (s0 * gdy + c0 * gdz);
      o[0] = t17x; o[1] = t17y; o[2] = t17z;  // row 17
      const float a14 = clampf(al[14], -0.349f, 0.349f);
      const float s14 = __sinf(a14), c14 = __cosf(a14);
      const float ux = g01, uy = c0 * g11 - s0 * g21, uz = s0 * g11 + c0 * g21;
      const float mx = s14 * g00 + c14 * g02;
      const float my = s14 * g10 + c14 * g12;
      const float mz = s14 * g20 + c14 * g22;
      const float vx = mx, vy = c0 * my - s0 * mz, vz = s0 * my + c0 * mz;
      const float g1 = clampf(al[15], 0.0f, 1.571f);
      const float g2 = g1 + clampf(al[16], 0.0f, 1.571f);
      const float g3 = g2 + clampf(al[17], 0.0f, 1.571f);
      const float s1 = __sinf(g1), c1 = __cosf(g1);
      const float s2 = __sinf(g2), c2 = __cosf(g2);
      const float s3 = __sinf(g3), c3 = __cosf(g3);
      const float q3y = -0.045f * s1, q3z = 0.045f * c1;
      const float q4y = q3y - 0.025f * s2, q4z = q3z + 0.025f * c2;
      const float q5y = q4y - 0.026f * s3, q5z = q4z + 0.026f * c3;
      o[3] = t17x + q3y * ux + q3z * vx;  // row 18
      o[4] = t17y + q3y * uy + q3z * vy;
      o[5] = t17z + q3y * uz + q3z * vz;
      o[6] = t17x + q4y * ux + q4z * vx;  // row 19
      o[7] = t17y + q4y * uy + q4z * vy;
      o[8] = t17z + q4y * uz + q4z * vz;
      o[9] = t17x + q5y * ux + q5z * vx;  // row 20
      o[10] = t17y + q5y * uy + q5z * vy;
      o[11] = t17z + q5y * uz + q5z * vz;
    } else {
      // thumb: Rz(-a18), Rx(a19), Rx(a20), Ry(a21), Ry(a22). Rows 1-4 -> o[0..11].
      const float a18 = clampf(al[18], -1.047f, 1.047f);
      const float s18 = __sinf(a18), c18 = __cosf(a18);
      const float t22x = 0.034f;
      const float t22y = -0.009f * c0 - 0.029f * s0;
      const float t22z = -0.009f * s0 + 0.029f * c0;
      o[0] = t22x; o[1] = t22y; o[2] = t22z;  // row 1 (node 22)
      const float a19 = clampf(al[19], 0.0f, 1.222f);
      const float a20 = clampf(al[20], -0.209f, 0.209f);
      const float a21 = clampf(al[21], -0.524f, 0.524f);
      const float a22 = clampf(al[22], -1.571f, 0.0f);
      const float s19 = __sinf(a19), c19 = __cosf(a19);
      const float sg = a19 + a20;
      const float ss = __sinf(sg), cs = __cosf(sg);
      const float s21 = __sinf(a21), c21 = __cosf(a21);
      const float ta = a21 + a22;
      const float st = __sinf(ta), ct = __cosf(ta);
      const float qAy = -0.038f * s19, qAz = 0.038f * c19;  // node 25
      const float q6x = 0.032f * s21;
      const float q6y = qAy - 0.032f * c21 * ss;
      const float q6z = qAz + 0.032f * c21 * cs;            // node 26
      const float q7x = q6x + 0.0275f * st;
      const float q7y = q6y - 0.0275f * ct * ss;
      const float q7z = q6z + 0.0275f * ct * cs;            // node 27
      const float m10 = c0 * s18, m11 = c0 * c18, m20 = s0 * s18, m21 = s0 * c18;
      o[3] = t22x + qAy * s18;                  // row 2 (node 25)
      o[4] = t22y + qAy * m11 - qAz * s0;
      o[5] = t22z + qAy * m21 + qAz * c0;
      o[6] = t22x + q6x * c18 + q6y * s18;      // row 3 (node 26)
      o[7] = t22y - q6x * m10 + q6y * m11 - q6z * s0;
      o[8] = t22z - q6x * m20 + q6y * m21 + q6z * c0;
      o[9] = t22x + q7x * c18 + q7y * s18;      // row 4 (node 27)
      o[10] = t22y - q7x * m10 + q7y * m11 - q7z * s0;
      o[11] = t22z - q7x * m20 + q7y * m21 + q7z * c0;
    }
#undef FINGER

    __syncthreads();  // all angle reads complete before output overwrites

    // ---- write this wave's floats into the element's 63-float LDS row.
    // Addresses (lane*63 + c): distinct banks across 32 lanes, 2-way alias
    // across 64 = free. ----
    {
      float* row = lds + lane * 63;
      if (w == 0) {
        row[0] = o[0]; row[1] = o[1]; row[2] = o[2];
#pragma unroll
        for (int k = 0; k < 12; ++k) row[15 + k] = o[3 + k];
      } else if (w == 1) {
#pragma unroll
        for (int k = 0; k < 24; ++k) row[27 + k] = o[k];
      } else if (w == 2) {
#pragma unroll
        for (int k = 0; k < 12; ++k) row[51 + k] = o[k];
      } else {
#pragma unroll
        for (int k = 0; k < 12; ++k) row[3 + k] = o[k];
      }
    }
    __syncthreads();

    // ---- coalesced nontemporal block store: 1008 f32x4 over 256 threads ----
    {
      const f32x4* lsrc = reinterpret_cast<const f32x4*>(lds);
      f32x4* gdst = reinterpret_cast<f32x4*>(out + base * 63);
#pragma unroll
      for (int k = 0; k < 4; ++k) {
        int idx = tid + k * TPB;
        if (idx < (EPB * 63) / 4)
          __builtin_nontemporal_store(lsrc[idx], gdst + idx);
      }
    }
  }
}

}  // namespace

extern "C" void kernel_launch(void* const* d_in, const int* in_sizes, int n_in,
                              void* d_out, int out_size, void* d_ws, size_t ws_size,
                              hipStream_t stream) {
  const float* angles = (const float*)d_in[0];
  float* out = (float*)d_out;
  const int Bn = in_sizes[0] / 23;           // 524288
  const int nblocks = Bn / (EPB * TILES);    // 2048 persistent blocks
  fk_kernel<<<nblocks, TPB, 0, stream>>>(angles, out);
}

// Round 7
// 33.089 us; speedup vs baseline: 2.0789x; 2.0789x over previous
//
#include <hip/hip_runtime.h>

namespace {

constexpr int TPB = 256;  // 4 waves; each wave computes one part of all 64 elements
constexpr int EPB = 64;   // elements per block

__device__ __forceinline__ float clampf(float x, float lo, float hi) {
  return fminf(fmaxf(x, lo), hi);
}

// All constants (axes, joint limits, translations) are static in the
// reference module and hard-coded/folded. 5 chains hang off node 0 (X-axis
// root rotation); consecutive X-rotations compose as cumulative angle sums.
//
// Wave-specialized: wave 0 = root + finger A, wave 1 = fingers B + C,
// wave 2 = little finger (metacarpal chain), wave 3 = thumb.
// R7 = exact revert to R4 (best: 33.0 us). R6 proved nontemporal stores
// regress 2x on gfx950 (store stream needs L2 write-combining); R3/R4
// proved occupancy/VGPR are not binding. 5.47 TB/s effective = mixed-stream
// HBM wall + ~4-5 us launch overhead on a ~28 us kernel.

__global__ __launch_bounds__(TPB, 8) void fk_kernel(
    const float* __restrict__ angles,
    float* __restrict__ out) {
  // 16128 B: angles staged in first 5888 B (64 x 23 f32), then the whole
  // buffer becomes 64 rows x 63 f32 of output staging.
  __shared__ float lds[EPB * 63];

  const int tid = threadIdx.x;
  const int lane = tid & 63;
  const int w = tid >> 6;  // wave id 0..3 (wave-uniform)
  const long long base = (long long)blockIdx.x * EPB;

  // ---- coalesced stage of this block's angles (368 float4, 256 threads) ----
  {
    const float4* __restrict__ src = reinterpret_cast<const float4*>(angles + base * 23);
    float4* dst = reinterpret_cast<float4*>(lds);
    dst[tid] = src[tid];                                   // 0..255
    if (tid + TPB < (EPB * 23) / 4) dst[tid + TPB] = src[tid + TPB];  // 256..367
  }
  __syncthreads();

  const float* al = lds + lane * 23;  // this wave's element = lane
  float o[24];                        // literal-indexed only

  const float a0 = clampf(al[0], -0.689f, 0.489f);
  const float s0 = __sinf(a0);
  const float c0 = __cosf(a0);

// ---- finger macro: t=(TX,0,TZ), Ry(knuckle al[J]), then 3x Rx with
// z-links 0.045/0.025/0.026. Writes o[OB..OB+11] (4 rows). ----
#define FINGER(TX, TZ, J, OB)                                                   \
  {                                                                             \
    const float aY = clampf(al[(J)], -0.349f, 0.349f);                          \
    const float sY = __sinf(aY), cY = __cosf(aY);                               \
    const float g1 = clampf(al[(J) + 1], 0.0f, 1.571f);                         \
    const float g2 = g1 + clampf(al[(J) + 2], 0.0f, 1.571f);                    \
    const float g3 = g2 + clampf(al[(J) + 3], 0.0f, 1.571f);                    \
    const float s1 = __sinf(g1), c1 = __cosf(g1);                               \
    const float s2 = __sinf(g2), c2 = __cosf(g2);                               \
    const float s3 = __sinf(g3), c3 = __cosf(g3);                               \
    const float t1x = (TX), t1y = -s0 * (TZ), t1z = c0 * (TZ);                  \
    const float vx = sY, vy = -s0 * cY, vz = c0 * cY; /* frame col2 */          \
    /* frame col1 = (0, c0, s0) */                                              \
    const float q3y = -0.045f * s1, q3z = 0.045f * c1;                          \
    const float q4y = q3y - 0.025f * s2, q4z = q3z + 0.025f * c2;               \
    const float q5y = q4y - 0.026f * s3, q5z = q4z + 0.026f * c3;               \
    o[(OB) + 0] = t1x; o[(OB) + 1] = t1y; o[(OB) + 2] = t1z;                    \
    o[(OB) + 3] = t1x + q3z * vx;                                               \
    o[(OB) + 4] = t1y + q3y * c0 + q3z * vy;                                    \
    o[(OB) + 5] = t1z + q3y * s0 + q3z * vz;                                    \
    o[(OB) + 6] = t1x + q4z * vx;                                               \
    o[(OB) + 7] = t1y + q4y * c0 + q4z * vy;                                    \
    o[(OB) + 8] = t1z + q4y * s0 + q4z * vz;                                    \
    o[(OB) + 9] = t1x + q5z * vx;                                               \
    o[(OB) + 10] = t1y + q5y * c0 + q5z * vy;                                   \
    o[(OB) + 11] = t1z + q5y * s0 + q5z * vz;                                   \
  }

  if (w == 0) {
    // root (row 0) + finger A (rows 5-8)
    o[0] = 0.0f; o[1] = 0.0f; o[2] = 0.0f;
    FINGER(0.033f, 0.095f, 1, 3)
  } else if (w == 1) {
    // finger B (rows 9-12) + finger C (rows 13-16)
    FINGER(0.011f, 0.099f, 5, 0)
    FINGER(-0.011f, 0.095f, 9, 12)
  } else if (w == 2) {
    // little finger w/ metacarpal: Rodrigues about w=(0.571,0,0.821),
    // then Ry, then 3x Rx. Rows 17-20 -> o[0..11].
    const float a13 = clampf(al[13], 0.0f, 0.785f);
    const float wx = 0.571f, wz = 0.821f;
    const float s13 = __sinf(a13), c13 = __cosf(a13);
    const float t13 = 1.0f - c13;
    const float g00 = 1.0f - t13 * (wz * wz), g10 = s13 * wz, g20 = t13 * (wx * wz);
    const float g01 = -s13 * wz, g11 = 1.0f - t13 * (wx * wx + wz * wz), g21 = s13 * wx;
    const float g02 = t13 * (wx * wz), g12 = -s13 * wx, g22 = 1.0f - t13 * (wx * wx);
    const float gdx = -0.017f * g00 + 0.044f * g02;
    const float gdy = -0.017f * g10 + 0.044f * g12;
    const float gdz = -0.017f * g20 + 0.044f * g22;
    const float t17x = -0.017f + gdx;
    const float t17y = -0.044f * s0 + (c0 * gdy - s0 * gdz);
    const float t17z = 0.044f * c0 + (s0 * gdy + c0 * gdz);
    o[0] = t17x; o[1] = t17y; o[2] = t17z;  // row 17
    const float a14 = clampf(al[14], -0.349f, 0.349f);
    const float s14 = __sinf(a14), c14 = __cosf(a14);
    const float ux = g01, uy = c0 * g11 - s0 * g21, uz = s0 * g11 + c0 * g21;
    const float mx = s14 * g00 + c14 * g02;
    const float my = s14 * g10 + c14 * g12;
    const float mz = s14 * g20 + c14 * g22;
    const float vx = mx, vy = c0 * my - s0 * mz, vz = s0 * my + c0 * mz;
    const float g1 = clampf(al[15], 0.0f, 1.571f);
    const float g2 = g1 + clampf(al[16], 0.0f, 1.571f);
    const float g3 = g2 + clampf(al[17], 0.0f, 1.571f);
    const float s1 = __sinf(g1), c1 = __cosf(g1);
    const float s2 = __sinf(g2), c2 = __cosf(g2);
    const float s3 = __sinf(g3), c3 = __cosf(g3);
    const float q3y = -0.045f * s1, q3z = 0.045f * c1;
    const float q4y = q3y - 0.025f * s2, q4z = q3z + 0.025f * c2;
    const float q5y = q4y - 0.026f * s3, q5z = q4z + 0.026f * c3;
    o[3] = t17x + q3y * ux + q3z * vx;  // row 18
    o[4] = t17y + q3y * uy + q3z * vy;
    o[5] = t17z + q3y * uz + q3z * vz;
    o[6] = t17x + q4y * ux + q4z * vx;  // row 19
    o[7] = t17y + q4y * uy + q4z * vy;
    o[8] = t17z + q4y * uz + q4z * vz;
    o[9] = t17x + q5y * ux + q5z * vx;  // row 20
    o[10] = t17y + q5y * uy + q5z * vy;
    o[11] = t17z + q5y * uz + q5z * vz;
  } else {
    // thumb: Rz(-a18), Rx(a19), Rx(a20), Ry(a21), Ry(a22). Rows 1-4 -> o[0..11].
    const float a18 = clampf(al[18], -1.047f, 1.047f);
    const float s18 = __sinf(a18), c18 = __cosf(a18);
    const float t22x = 0.034f;
    const float t22y = -0.009f * c0 - 0.029f * s0;
    const float t22z = -0.009f * s0 + 0.029f * c0;
    o[0] = t22x; o[1] = t22y; o[2] = t22z;  // row 1 (node 22)
    const float a19 = clampf(al[19], 0.0f, 1.222f);
    const float a20 = clampf(al[20], -0.209f, 0.209f);
    const float a21 = clampf(al[21], -0.524f, 0.524f);
    const float a22 = clampf(al[22], -1.571f, 0.0f);
    const float s19 = __sinf(a19), c19 = __cosf(a19);
    const float sg = a19 + a20;
    const float ss = __sinf(sg), cs = __cosf(sg);
    const float s21 = __sinf(a21), c21 = __cosf(a21);
    const float ta = a21 + a22;
    const float st = __sinf(ta), ct = __cosf(ta);
    const float qAy = -0.038f * s19, qAz = 0.038f * c19;  // node 25
    const float q6x = 0.032f * s21;
    const float q6y = qAy - 0.032f * c21 * ss;
    const float q6z = qAz + 0.032f * c21 * cs;            // node 26
    const float q7x = q6x + 0.0275f * st;
    const float q7y = q6y - 0.0275f * ct * ss;
    const float q7z = q6z + 0.0275f * ct * cs;            // node 27
    const float m10 = c0 * s18, m11 = c0 * c18, m20 = s0 * s18, m21 = s0 * c18;
    o[3] = t22x + qAy * s18;                  // row 2 (node 25)
    o[4] = t22y + qAy * m11 - qAz * s0;
    o[5] = t22z + qAy * m21 + qAz * c0;
    o[6] = t22x + q6x * c18 + q6y * s18;      // row 3 (node 26)
    o[7] = t22y - q6x * m10 + q6y * m11 - q6z * s0;
    o[8] = t22z - q6x * m20 + q6y * m21 + q6z * c0;
    o[9] = t22x + q7x * c18 + q7y * s18;      // row 4 (node 27)
    o[10] = t22y - q7x * m10 + q7y * m11 - q7z * s0;
    o[11] = t22z - q7x * m20 + q7y * m21 + q7z * c0;
  }
#undef FINGER

  __syncthreads();  // all angle reads complete before output overwrites

  // ---- write this wave's floats into the element's 63-float LDS row.
  // Addresses (lane*63 + c): distinct banks across 32 lanes, 2-way alias
  // across 64 = free. ----
  {
    float* row = lds + lane * 63;
    if (w == 0) {
      row[0] = o[0]; row[1] = o[1]; row[2] = o[2];
#pragma unroll
      for (int k = 0; k < 12; ++k) row[15 + k] = o[3 + k];
    } else if (w == 1) {
#pragma unroll
      for (int k = 0; k < 24; ++k) row[27 + k] = o[k];
    } else if (w == 2) {
#pragma unroll
      for (int k = 0; k < 12; ++k) row[51 + k] = o[k];
    } else {
#pragma unroll
      for (int k = 0; k < 12; ++k) row[3 + k] = o[k];
    }
  }
  __syncthreads();

  // ---- coalesced block store: 1008 float4 over 256 threads ----
  {
    const float4* lsrc = reinterpret_cast<const float4*>(lds);
    float4* gdst = reinterpret_cast<float4*>(out + base * 63);
#pragma unroll
    for (int k = 0; k < 4; ++k) {
      int idx = tid + k * TPB;
      if (idx < (EPB * 63) / 4) gdst[idx] = lsrc[idx];
    }
  }
}

}  // namespace

extern "C" void kernel_launch(void* const* d_in, const int* in_sizes, int n_in,
                              void* d_out, int out_size, void* d_ws, size_t ws_size,
                              hipStream_t stream) {
  const float* angles = (const float*)d_in[0];
  float* out = (float*)d_out;
  const int Bn = in_sizes[0] / 23;   // 524288
  const int nblocks = Bn / EPB;      // 8192
  fk_kernel<<<nblocks, TPB, 0, stream>>>(angles, out);
}